// Round 3
// baseline (908.851 us; speedup 1.0000x reference)
//
#include <hip/hip_runtime.h>
#include <hip/hip_cooperative_groups.h>

namespace cg = cooperative_groups;

#define N_NODES 100000
#define N_EDGES 1000000
#define K_TOT   320            // 128 (x) + 128 (agg_x) + 64 (agg_t)

#define CSR_GRID 512
#define CSR_NPB  196           // ceil(N_NODES / CSR_GRID)

#define BM  128
#define BN  128
#define BK  64
#define LDA 72                 // padded LDS row stride (bf16 elems) — breaks 32-bank stride

typedef __attribute__((ext_vector_type(8))) short bf16x8;
typedef __attribute__((ext_vector_type(4))) float f32x4;

__device__ __forceinline__ unsigned short f2bf(float f) {
    unsigned u = __float_as_uint(f);
    u += 0x7FFFu + ((u >> 16) & 1u);          // round-to-nearest-even
    return (unsigned short)(u >> 16);
}
__device__ __forceinline__ unsigned pack2(float a, float b) {
    return (unsigned)f2bf(a) | ((unsigned)f2bf(b) << 16);
}

// ---------------------------------------------------------------------------
// One cooperative kernel: prep weights (bf16) + zero hist + histogram +
// hierarchical scan -> offsets/cursor + fill ec[pos] = (col,e).
// ---------------------------------------------------------------------------
__global__ __launch_bounds__(256, 2) void csr_kernel(
        const int*   __restrict__ ei,
        const float* __restrict__ WSw, const float* __restrict__ WTw,
        const float* __restrict__ Tw,  const float* __restrict__ WTb,
        const float* __restrict__ Tb,
        unsigned short* __restrict__ Gtb, float* __restrict__ bias2,
        int* __restrict__ hist, int* __restrict__ offsets,
        int* __restrict__ cursor, int* __restrict__ csum,
        unsigned long long* __restrict__ ec) {
    cg::grid_group grid = cg::this_grid();
    int b = blockIdx.x, t = threadIdx.x;
    int gtid = b * 256 + t;
    const int GT = CSR_GRID * 256;

    __shared__ int ts[256];

    // phase 0: zero hist, build Gtb[o][k] (k-contiguous bf16), bias2
    for (int i = gtid; i < N_NODES; i += GT) hist[i] = 0;
    for (int idx = gtid; idx < K_TOT * 128; idx += GT) {
        int k = idx >> 7, o = idx & 127;
        float v = (k < 128) ? WSw[o * 128 + k]
                : (k < 256) ? WTw[o * 128 + (k - 128)]
                            : Tw[o * 64 + (k - 256)];
        Gtb[(size_t)o * K_TOT + k] = f2bf(v);
    }
    if (gtid < 128) bias2[gtid] = WTb[gtid] + Tb[gtid];
    if (gtid == 0) offsets[N_NODES] = N_EDGES;
    grid.sync();

    // phase 1: histogram of destination rows
    for (int e = gtid; e < N_EDGES; e += GT) atomicAdd(&hist[ei[e]], 1);
    grid.sync();

    // phase 2a: per-block range sums
    int n0 = b * CSR_NPB;
    int cnt = N_NODES - n0;                    // may be <=0 for tail blocks
    if (cnt > CSR_NPB) cnt = CSR_NPB;
    int v = (t < cnt) ? hist[n0 + t] : 0;
    ts[t] = v;
    __syncthreads();
    for (int off = 128; off; off >>= 1) {
        if (t < off) ts[t] += ts[t + off];
        __syncthreads();
    }
    if (t == 0) csum[b] = ts[0];
    grid.sync();

    // phase 2b: block 0 exclusive-scans csum[512] in place
    if (b == 0) {
        int a0 = csum[2 * t], a1 = csum[2 * t + 1];
        ts[t] = a0 + a1;
        __syncthreads();
        for (int off = 1; off < 256; off <<= 1) {
            int add = (t >= off) ? ts[t - off] : 0;
            __syncthreads();
            ts[t] += add;
            __syncthreads();
        }
        int excl = ts[t] - (a0 + a1);
        csum[2 * t]     = excl;
        csum[2 * t + 1] = excl + a0;
    }
    grid.sync();

    // phase 2c: block-local exclusive scan -> offsets + cursor
    int base = csum[b];
    ts[t] = v;
    __syncthreads();
    for (int off = 1; off < 256; off <<= 1) {
        int add = (t >= off) ? ts[t - off] : 0;
        __syncthreads();
        ts[t] += add;
        __syncthreads();
    }
    if (t < cnt) {
        int ex = base + ts[t] - v;
        offsets[n0 + t] = ex;
        cursor[n0 + t]  = ex;
    }
    grid.sync();

    // phase 3: fill ec[pos] = (col << 32) | e
    for (int e = gtid; e < N_EDGES; e += GT) {
        int row = ei[e];
        int col = ei[N_EDGES + e];
        int pos = atomicAdd(&cursor[row], 1);
        ec[pos] = ((unsigned long long)(unsigned)col << 32) | (unsigned)e;
    }
}

// ---------------------------------------------------------------------------
// Segment reduce: one wave per node, 2 edges per iteration (MLP).
// Writes aggx (=d_out), aggt, deg exactly once each.
// ---------------------------------------------------------------------------
__global__ __launch_bounds__(256) void agg_kernel(
        const float* __restrict__ x,
        const float* __restrict__ tf,
        const unsigned long long* __restrict__ ec,
        const int* __restrict__ offsets,
        float* __restrict__ aggx,
        float* __restrict__ aggt,
        float* __restrict__ deg) {
    int lane = threadIdx.x & 63;
    int n = blockIdx.x * 4 + (threadIdx.x >> 6);
    if (n >= N_NODES) return;

    int beg = offsets[n], end = offsets[n + 1];

    float ax0 = 0.f, ax1 = 0.f, at0 = 0.f;
    float bx0 = 0.f, bx1 = 0.f, bt0 = 0.f;

    int i = beg;
    for (; i + 1 < end; i += 2) {
        unsigned long long p0 = ec[i], p1 = ec[i + 1];
        const float* xp0 = x + ((size_t)(p0 >> 32) << 7);
        const float* xp1 = x + ((size_t)(p1 >> 32) << 7);
        const float* tp0 = tf + ((size_t)(unsigned)p0 << 6);
        const float* tp1 = tf + ((size_t)(unsigned)p1 << 6);
        float a = xp0[lane], bq = xp0[64 + lane];
        float c = xp1[lane], d  = xp1[64 + lane];
        float u = __builtin_nontemporal_load(tp0 + lane);
        float w = __builtin_nontemporal_load(tp1 + lane);
        ax0 += a; ax1 += bq; at0 += u;
        bx0 += c; bx1 += d;  bt0 += w;
    }
    if (i < end) {
        unsigned long long p0 = ec[i];
        const float* xp0 = x + ((size_t)(p0 >> 32) << 7);
        ax0 += xp0[lane];
        ax1 += xp0[64 + lane];
        at0 += __builtin_nontemporal_load(tf + ((size_t)(unsigned)p0 << 6) + lane);
    }

    aggx[(size_t)n * 128 + lane]      = ax0 + bx0;
    aggx[(size_t)n * 128 + 64 + lane] = ax1 + bx1;
    aggt[(size_t)n * 64 + lane]       = at0 + bt0;
    if (lane == 0) deg[n] = (float)(end - beg);
}

// ---------------------------------------------------------------------------
// MFMA bf16 GEMM: out = relu([x | aggx | aggt] @ Gtb^T + WSb + deg*bias2)
// 128x128 block, BK=64, 4 waves each computing 64x64 via 4x4 of 16x16x32.
// A converted fp32->bf16 during LDS staging. aggx aliases out: each block
// reads only its own rows, all reads precede the epilogue stores.
// ---------------------------------------------------------------------------
__global__ __launch_bounds__(256) void gemm_kernel(
        const float* __restrict__ x,
        const float* aggx,                     // = out (aliased, no restrict)
        const float* __restrict__ aggt,
        const unsigned short* __restrict__ Gtb,
        const float* __restrict__ WSb,
        const float* __restrict__ bias2,
        const float* __restrict__ deg,
        float* out) {
    __shared__ unsigned short As[BM * LDA];
    __shared__ unsigned short Bs[BN * LDA];

    int t = threadIdx.x;
    int lane = t & 63;
    int wave = t >> 6;
    int mw = (wave & 1) * 64;
    int nw = (wave >> 1) * 64;
    int row0 = blockIdx.x * BM;
    int quad = lane >> 4;
    int l16  = lane & 15;

    f32x4 acc[4][4];
#pragma unroll
    for (int mt = 0; mt < 4; ++mt)
#pragma unroll
        for (int nt = 0; nt < 4; ++nt)
            acc[mt][nt] = (f32x4){0.f, 0.f, 0.f, 0.f};

    int sm = t >> 1;            // staging row 0..127
    int sh = (t & 1) * 32;      // staging k-half offset

    for (int c = 0; c < 5; ++c) {
        const float* src; int ld, koff;
        if (c < 2)      { src = x;    ld = 128; koff = c * 64; }
        else if (c < 4) { src = aggx; ld = 128; koff = (c - 2) * 64; }
        else            { src = aggt; ld = 64;  koff = 0; }

        __syncthreads();        // previous iteration's LDS reads done

        int gm = row0 + sm;
        const float* ap = src + (size_t)gm * ld + koff + sh;
#pragma unroll
        for (int g = 0; g < 4; ++g) {
            float4 u0 = {0.f, 0.f, 0.f, 0.f}, u1 = u0;
            if (gm < N_NODES) {
                u0 = *(const float4*)(ap + g * 8);
                u1 = *(const float4*)(ap + g * 8 + 4);
            }
            uint4 w;
            w.x = pack2(u0.x, u0.y);
            w.y = pack2(u0.z, u0.w);
            w.z = pack2(u1.x, u1.y);
            w.w = pack2(u1.z, u1.w);
            *(uint4*)&As[sm * LDA + sh + g * 8] = w;
        }

        const unsigned short* gp = Gtb + (size_t)sm * K_TOT + c * 64 + sh;
#pragma unroll
        for (int g = 0; g < 4; ++g)
            *(uint4*)&Bs[sm * LDA + sh + g * 8] = *(const uint4*)(gp + g * 8);

        __syncthreads();

#pragma unroll
        for (int ks = 0; ks < 2; ++ks) {
            bf16x8 af[4], bfv[4];
#pragma unroll
            for (int mt = 0; mt < 4; ++mt)
                af[mt] = *(bf16x8*)&As[(mw + mt * 16 + l16) * LDA + ks * 32 + quad * 8];
#pragma unroll
            for (int nt = 0; nt < 4; ++nt)
                bfv[nt] = *(bf16x8*)&Bs[(nw + nt * 16 + l16) * LDA + ks * 32 + quad * 8];
#pragma unroll
            for (int mt = 0; mt < 4; ++mt)
#pragma unroll
                for (int nt = 0; nt < 4; ++nt)
                    acc[mt][nt] = __builtin_amdgcn_mfma_f32_16x16x32_bf16(
                        af[mt], bfv[nt], acc[mt][nt], 0, 0, 0);
        }
    }

    // epilogue: bias + deg*bias2 + ReLU
#pragma unroll
    for (int mt = 0; mt < 4; ++mt) {
#pragma unroll
        for (int r = 0; r < 4; ++r) {
            int m = row0 + mw + mt * 16 + quad * 4 + r;
            if (m >= N_NODES) continue;
            float dg = deg[m];
#pragma unroll
            for (int nt = 0; nt < 4; ++nt) {
                int o = nw + nt * 16 + l16;
                float val = acc[mt][nt][r] + WSb[o] + dg * bias2[o];
                out[(size_t)m * 128 + o] = fmaxf(val, 0.f);
            }
        }
    }
}

// ---------------------------------------------------------------------------
extern "C" void kernel_launch(void* const* d_in, const int* in_sizes, int n_in,
                              void* d_out, int out_size, void* d_ws, size_t ws_size,
                              hipStream_t stream) {
    const float* x   = (const float*)d_in[0];
    const int*   ei  = (const int*)d_in[1];
    const float* tf  = (const float*)d_in[2];
    const float* WSw = (const float*)d_in[3];
    const float* WSb = (const float*)d_in[4];
    const float* WTw = (const float*)d_in[5];
    const float* WTb = (const float*)d_in[6];
    const float* Tw  = (const float*)d_in[7];
    const float* Tb  = (const float*)d_in[8];
    float* out = (float*)d_out;

    // Workspace layout (~35.7 MB):
    float* aggt  = (float*)d_ws;                               // 100000*64 f
    float* deg   = aggt + (size_t)N_NODES * 64;                // 100000 f
    float* bias2 = deg + N_NODES;                              // 128 f
    unsigned short* Gtb = (unsigned short*)(bias2 + 128);      // 320*128 bf16
    int* hist    = (int*)(Gtb + (size_t)K_TOT * 128);          // 100000 i
    int* offsets = hist + N_NODES;                             // 100002 i (pad for 8B align)
    int* cursor  = offsets + (N_NODES + 2);                    // 100000 i
    int* csum    = cursor + N_NODES;                           // 512 i
    unsigned long long* ec = (unsigned long long*)(csum + CSR_GRID);  // 1M u64

    float* aggx = out;   // reuse output buffer as agg_x accumulator

    void* cargs[] = {
        (void*)&ei, (void*)&WSw, (void*)&WTw, (void*)&Tw, (void*)&WTb,
        (void*)&Tb, (void*)&Gtb, (void*)&bias2, (void*)&hist,
        (void*)&offsets, (void*)&cursor, (void*)&csum, (void*)&ec};
    hipLaunchCooperativeKernel((void*)csr_kernel, dim3(CSR_GRID), dim3(256),
                               cargs, 0, stream);

    agg_kernel<<<N_NODES / 4, 256, 0, stream>>>(
        x, tf, ec, offsets, aggx, aggt, deg);

    gemm_kernel<<<(N_NODES + BM - 1) / BM, 256, 0, stream>>>(
        x, aggx, aggt, Gtb, WSb, bias2, deg, out);
}

// Round 4
// 627.444 us; speedup vs baseline: 1.4485x; 1.4485x over previous
//
#include <hip/hip_runtime.h>

#define N_NODES 100000
#define N_EDGES 1000000
#define K_TOT   320     // 128 (x) + 128 (agg_x) + 64 (agg_t)
#define NCHUNK  98      // ceil(100000/1024)

#define BM  128
#define LDA 72          // padded LDS row stride (bf16 elems)

typedef __attribute__((ext_vector_type(8))) short bf16x8;
typedef __attribute__((ext_vector_type(4))) float f32x4;

__device__ __forceinline__ unsigned short f2bf(float f) {
    unsigned u = __float_as_uint(f);
    u += 0x7FFFu + ((u >> 16) & 1u);          // round-to-nearest-even
    return (unsigned short)(u >> 16);
}
__device__ __forceinline__ unsigned pack2(float a, float b) {
    return (unsigned)f2bf(a) | ((unsigned)f2bf(b) << 16);
}

// ---------------------------------------------------------------------------
// Prep: Gtb[o][k] (k-contiguous bf16, k = 0..319) and bias2 = WTb+Tb
// ---------------------------------------------------------------------------
__global__ void prep_kernel(const float* __restrict__ WSw,
                            const float* __restrict__ WTw,
                            const float* __restrict__ Tw,
                            const float* __restrict__ WTb,
                            const float* __restrict__ Tb,
                            unsigned short* __restrict__ Gtb,
                            float* __restrict__ bias2) {
    int idx = blockIdx.x * 256 + threadIdx.x;
    if (idx < K_TOT * 128) {
        int k = idx >> 7;
        int o = idx & 127;
        float v = (k < 128) ? WSw[o * 128 + k]
                : (k < 256) ? WTw[o * 128 + (k - 128)]
                            : Tw[o * 64 + (k - 256)];
        Gtb[(size_t)o * K_TOT + k] = f2bf(v);
    }
    if (idx < 128) bias2[idx] = WTb[idx] + Tb[idx];
}

// ---------------------------------------------------------------------------
// CSR build: histogram -> scan -> fill ec[pos] = (col,e)   (full-size grids)
// ---------------------------------------------------------------------------
__global__ __launch_bounds__(256) void hist_kernel(const int* __restrict__ ei,
                                                   int* __restrict__ hist) {
    int e = blockIdx.x * 256 + threadIdx.x;
    if (e < N_EDGES) atomicAdd(&hist[ei[e]], 1);
}

__global__ __launch_bounds__(256) void scan_pass1(const int* __restrict__ hist,
                                                  int* __restrict__ chunksum) {
    __shared__ int ts[256];
    int b = blockIdx.x, t = threadIdx.x;
    int i = b * 1024 + t * 4;
    int s = 0;
#pragma unroll
    for (int j = 0; j < 4; ++j)
        if (i + j < N_NODES) s += hist[i + j];
    ts[t] = s;
    __syncthreads();
    for (int off = 128; off > 0; off >>= 1) {
        if (t < off) ts[t] += ts[t + off];
        __syncthreads();
    }
    if (t == 0) chunksum[b] = ts[0];
}

__global__ void scan_mid(const int* __restrict__ chunksum,
                         int* __restrict__ chunkoff) {
    if (threadIdx.x == 0 && blockIdx.x == 0) {
        int run = 0;
        for (int i = 0; i < NCHUNK; ++i) { chunkoff[i] = run; run += chunksum[i]; }
    }
}

__global__ __launch_bounds__(256) void scan_pass2(const int* __restrict__ hist,
                                                  const int* __restrict__ chunkoff,
                                                  int* __restrict__ offsets) {
    __shared__ int ts[256];
    int b = blockIdx.x, t = threadIdx.x;
    int i0 = b * 1024 + t * 4;
    int v[4];
    int s = 0;
#pragma unroll
    for (int j = 0; j < 4; ++j) {
        v[j] = (i0 + j < N_NODES) ? hist[i0 + j] : 0;
        s += v[j];
    }
    ts[t] = s;
    __syncthreads();
    for (int off = 1; off < 256; off <<= 1) {
        int add = (t >= off) ? ts[t - off] : 0;
        __syncthreads();
        ts[t] += add;
        __syncthreads();
    }
    int run = chunkoff[b] + ts[t] - s;   // exclusive base for this thread
#pragma unroll
    for (int j = 0; j < 4; ++j) {
        if (i0 + j < N_NODES) offsets[i0 + j] = run;
        run += v[j];
    }
    if (b == 0 && t == 0) offsets[N_NODES] = N_EDGES;
}

__global__ __launch_bounds__(256) void fill_kernel(const int* __restrict__ ei,
                                                   int* __restrict__ cursor,
                                                   unsigned long long* __restrict__ ec) {
    int e = blockIdx.x * 256 + threadIdx.x;
    if (e < N_EDGES) {
        int row = ei[e];
        int col = ei[N_EDGES + e];
        int pos = atomicAdd(&cursor[row], 1);
        ec[pos] = ((unsigned long long)(unsigned)col << 32) | (unsigned)e;
    }
}

// ---------------------------------------------------------------------------
// Segment reduce: one wave per node, 4 edges per iteration (MLP).
// Writes aggx (=d_out), aggt, deg exactly once each — no memset needed.
// ---------------------------------------------------------------------------
__global__ __launch_bounds__(256) void agg_kernel(
        const float* __restrict__ x,
        const float* __restrict__ tf,
        const unsigned long long* __restrict__ ec,
        const int* __restrict__ offsets,
        float* __restrict__ aggx,
        float* __restrict__ aggt,
        float* __restrict__ deg) {
    int lane = threadIdx.x & 63;
    int n = blockIdx.x * 4 + (threadIdx.x >> 6);
    if (n >= N_NODES) return;

    int beg = offsets[n], end = offsets[n + 1];

    float ax0 = 0.f, ax1 = 0.f, at0 = 0.f;
    float bx0 = 0.f, bx1 = 0.f, bt0 = 0.f;

    int i = beg;
    for (; i + 3 < end; i += 4) {
        unsigned long long p0 = ec[i],     p1 = ec[i + 1];
        unsigned long long p2 = ec[i + 2], p3 = ec[i + 3];
        const float* x0p = x + ((size_t)(p0 >> 32) << 7);
        const float* x1p = x + ((size_t)(p1 >> 32) << 7);
        const float* x2p = x + ((size_t)(p2 >> 32) << 7);
        const float* x3p = x + ((size_t)(p3 >> 32) << 7);
        const float* t0p = tf + ((size_t)(unsigned)p0 << 6);
        const float* t1p = tf + ((size_t)(unsigned)p1 << 6);
        const float* t2p = tf + ((size_t)(unsigned)p2 << 6);
        const float* t3p = tf + ((size_t)(unsigned)p3 << 6);
        float a0 = x0p[lane], a1 = x0p[64 + lane];
        float b0 = x1p[lane], b1 = x1p[64 + lane];
        float c0 = x2p[lane], c1 = x2p[64 + lane];
        float d0 = x3p[lane], d1 = x3p[64 + lane];
        float u0 = __builtin_nontemporal_load(t0p + lane);
        float u1 = __builtin_nontemporal_load(t1p + lane);
        float u2 = __builtin_nontemporal_load(t2p + lane);
        float u3 = __builtin_nontemporal_load(t3p + lane);
        ax0 += a0; ax1 += a1; at0 += u0;
        bx0 += b0; bx1 += b1; bt0 += u1;
        ax0 += c0; ax1 += c1; at0 += u2;
        bx0 += d0; bx1 += d1; bt0 += u3;
    }
    for (; i < end; ++i) {
        unsigned long long p0 = ec[i];
        const float* xp = x + ((size_t)(p0 >> 32) << 7);
        ax0 += xp[lane];
        ax1 += xp[64 + lane];
        at0 += __builtin_nontemporal_load(tf + ((size_t)(unsigned)p0 << 6) + lane);
    }

    aggx[(size_t)n * 128 + lane]      = ax0 + bx0;
    aggx[(size_t)n * 128 + 64 + lane] = ax1 + bx1;
    aggt[(size_t)n * 64 + lane]       = at0 + bt0;
    if (lane == 0) deg[n] = (float)(end - beg);
}

// ---------------------------------------------------------------------------
// MFMA bf16 GEMM: out = relu([x | aggx | aggt] @ Gtb^T + WSb + deg*bias2)
// 128x128 block, BK=64, 4 waves each computing 64x64 via 4x4 of 16x16x32.
// aggx aliases out: each block reads only its own rows; all reads precede
// the epilogue stores.
// ---------------------------------------------------------------------------
__global__ __launch_bounds__(256) void gemm_kernel(
        const float* __restrict__ x,
        const float* aggx,                     // = out (aliased, no restrict)
        const float* __restrict__ aggt,
        const unsigned short* __restrict__ Gtb,
        const float* __restrict__ WSb,
        const float* __restrict__ bias2,
        const float* __restrict__ deg,
        float* out) {
    __shared__ unsigned short As[BM * LDA];
    __shared__ unsigned short Bs[BM * LDA];

    int t = threadIdx.x;
    int lane = t & 63;
    int wave = t >> 6;
    int mw = (wave & 1) * 64;
    int nw = (wave >> 1) * 64;
    int row0 = blockIdx.x * BM;
    int quad = lane >> 4;
    int l16  = lane & 15;

    f32x4 acc[4][4];
#pragma unroll
    for (int mt = 0; mt < 4; ++mt)
#pragma unroll
        for (int nt = 0; nt < 4; ++nt)
            acc[mt][nt] = (f32x4){0.f, 0.f, 0.f, 0.f};

    int sm = t >> 1;            // staging row 0..127
    int sh = (t & 1) * 32;      // staging k-half offset

    for (int c = 0; c < 5; ++c) {
        const float* src; int ld, koff;
        if (c < 2)      { src = x;    ld = 128; koff = c * 64; }
        else if (c < 4) { src = aggx; ld = 128; koff = (c - 2) * 64; }
        else            { src = aggt; ld = 64;  koff = 0; }

        __syncthreads();        // previous iteration's LDS reads done

        int gm = row0 + sm;
        const float* ap = src + (size_t)gm * ld + koff + sh;
#pragma unroll
        for (int g = 0; g < 4; ++g) {
            float4 u0 = {0.f, 0.f, 0.f, 0.f}, u1 = u0;
            if (gm < N_NODES) {
                u0 = *(const float4*)(ap + g * 8);
                u1 = *(const float4*)(ap + g * 8 + 4);
            }
            uint4 w;
            w.x = pack2(u0.x, u0.y);
            w.y = pack2(u0.z, u0.w);
            w.z = pack2(u1.x, u1.y);
            w.w = pack2(u1.z, u1.w);
            *(uint4*)&As[sm * LDA + sh + g * 8] = w;
        }

        const unsigned short* gp = Gtb + (size_t)sm * K_TOT + c * 64 + sh;
#pragma unroll
        for (int g = 0; g < 4; ++g)
            *(uint4*)&Bs[sm * LDA + sh + g * 8] = *(const uint4*)(gp + g * 8);

        __syncthreads();

#pragma unroll
        for (int ks = 0; ks < 2; ++ks) {
            bf16x8 af[4], bfv[4];
#pragma unroll
            for (int mt = 0; mt < 4; ++mt)
                af[mt] = *(bf16x8*)&As[(mw + mt * 16 + l16) * LDA + ks * 32 + quad * 8];
#pragma unroll
            for (int nt = 0; nt < 4; ++nt)
                bfv[nt] = *(bf16x8*)&Bs[(nw + nt * 16 + l16) * LDA + ks * 32 + quad * 8];
#pragma unroll
            for (int mt = 0; mt < 4; ++mt)
#pragma unroll
                for (int nt = 0; nt < 4; ++nt)
                    acc[mt][nt] = __builtin_amdgcn_mfma_f32_16x16x32_bf16(
                        af[mt], bfv[nt], acc[mt][nt], 0, 0, 0);
        }
    }

    // epilogue: bias + deg*bias2 + ReLU
#pragma unroll
    for (int mt = 0; mt < 4; ++mt) {
#pragma unroll
        for (int r = 0; r < 4; ++r) {
            int m = row0 + mw + mt * 16 + quad * 4 + r;
            if (m >= N_NODES) continue;
            float dg = deg[m];
#pragma unroll
            for (int nt = 0; nt < 4; ++nt) {
                int o = nw + nt * 16 + l16;
                float val = acc[mt][nt][r] + WSb[o] + dg * bias2[o];
                out[(size_t)m * 128 + o] = fmaxf(val, 0.f);
            }
        }
    }
}

// ---------------------------------------------------------------------------
extern "C" void kernel_launch(void* const* d_in, const int* in_sizes, int n_in,
                              void* d_out, int out_size, void* d_ws, size_t ws_size,
                              hipStream_t stream) {
    const float* x   = (const float*)d_in[0];
    const int*   ei  = (const int*)d_in[1];
    const float* tf  = (const float*)d_in[2];
    const float* WSw = (const float*)d_in[3];
    const float* WSb = (const float*)d_in[4];
    const float* WTw = (const float*)d_in[5];
    const float* WTb = (const float*)d_in[6];
    const float* Tw  = (const float*)d_in[7];
    const float* Tb  = (const float*)d_in[8];
    float* out = (float*)d_out;

    // Workspace layout (~35 MB), all offsets 8B-aligned:
    float* aggt  = (float*)d_ws;                               // 100000*64 f
    float* deg   = aggt + (size_t)N_NODES * 64;                // 100000 f
    float* bias2 = deg + N_NODES;                              // 128 f
    unsigned short* Gtb = (unsigned short*)(bias2 + 128);      // 320*128 bf16
    int* hist    = (int*)(Gtb + (size_t)K_TOT * 128);          // 100000 i
    int* offsets = hist + N_NODES;                             // 100002 i
    int* cursor  = offsets + (N_NODES + 2);                    // 100000 i
    int* csum    = cursor + N_NODES;                           // 100 i
    int* coff    = csum + 100;                                 // 100 i
    unsigned long long* ec = (unsigned long long*)(coff + 100);// 1M u64

    float* aggx = out;   // reuse output buffer as agg_x accumulator

    hipMemsetAsync(hist, 0, (size_t)N_NODES * sizeof(int), stream);

    prep_kernel<<<(K_TOT * 128 + 255) / 256, 256, 0, stream>>>(
        WSw, WTw, Tw, WTb, Tb, Gtb, bias2);

    hist_kernel<<<(N_EDGES + 255) / 256, 256, 0, stream>>>(ei, hist);
    scan_pass1<<<NCHUNK, 256, 0, stream>>>(hist, csum);
    scan_mid<<<1, 64, 0, stream>>>(csum, coff);
    scan_pass2<<<NCHUNK, 256, 0, stream>>>(hist, coff, offsets);

    hipMemcpyAsync(cursor, offsets, (size_t)N_NODES * sizeof(int),
                   hipMemcpyDeviceToDevice, stream);

    fill_kernel<<<(N_EDGES + 255) / 256, 256, 0, stream>>>(ei, cursor, ec);

    agg_kernel<<<N_NODES / 4, 256, 0, stream>>>(
        x, tf, ec, offsets, aggx, aggt, deg);

    gemm_kernel<<<(N_NODES + BM - 1) / BM, 256, 0, stream>>>(
        x, aggx, aggt, Gtb, WSb, bias2, deg, out);
}